// Round 7
// baseline (202.604 us; speedup 1.0000x reference)
//
#include <hip/hip_runtime.h>
#include <hip/hip_bf16.h>
#include <math.h>

// ---------------------------------------------------------------------------
// HoloKVSimulatorLayer fused pipeline, bf16 MFMA, MI355X (gfx950)
//   B=2 S=2048 H=1024 NH=NKV=16 HD=64 R=16 KF=4 theta=1e6
// R5: attn_fwd — 1024 blocks LPT (qt=31-bx), swapped PV (stats in-lane,
// no bpermute), exact rescale-skip, setprio around MFMA. K/V dbuf + counted
// vmcnt kept from R3.
// ---------------------------------------------------------------------------

typedef __bf16 bf16;
typedef __attribute__((ext_vector_type(8))) __bf16 bf16x8;
typedef __attribute__((ext_vector_type(4))) float f32x4;

#define NB 2
#define SEQ 2048
#define HID 1024
#define NHD 16
#define HDD 64

__device__ __forceinline__ void gld_lds16(const void* g, void* l) {
  __builtin_amdgcn_global_load_lds(
      (const __attribute__((address_space(1))) void*)g,
      (__attribute__((address_space(3))) void*)l, 16, 0, 0);
}

__device__ __forceinline__ unsigned pack2bf(float a, float b) {
  unsigned short ua = __builtin_bit_cast(unsigned short, (bf16)a);
  unsigned short ub = __builtin_bit_cast(unsigned short, (bf16)b);
  return ((unsigned)ub << 16) | ua;
}

// ---------------- P0: fold LoRA into weights, swizzle, bf16 ----------------
__global__ __launch_bounds__(256) void prep_wqkv(
    const float* __restrict__ qw, const float* __restrict__ kw,
    const float* __restrict__ vw, const float* __restrict__ qA,
    const float* __restrict__ qB, const float* __restrict__ vA,
    const float* __restrict__ vB, bf16* __restrict__ W) {
  int idx = blockIdx.x * 256 + threadIdx.x;   // n*1024 + k, n in [0,3072)
  if (idx >= 3072 * 1024) return;
  int n = idx >> 10, k = idx & 1023;
  float v;
  if (n < 1024) {
    v = qw[n * 1024 + k];
#pragma unroll
    for (int r = 0; r < 16; ++r) v += qB[n * 16 + r] * qA[r * 1024 + k];
  } else if (n < 2048) {
    v = kw[(n - 1024) * 1024 + k];
  } else {
    int nn = n - 2048;
    v = vw[nn * 1024 + k];
#pragma unroll
    for (int r = 0; r < 16; ++r) v += vB[nn * 16 + r] * vA[r * 1024 + k];
  }
  int seg = k >> 6, cl = k & 63;
  int ch = (cl >> 3) ^ (n & 7);
  W[(size_t)n * 1024 + (seg << 6) + (ch << 3) + (cl & 7)] = (bf16)v;
}

// ---------------- P1: f32 -> bf16 with global pre-swizzle ------------------
__global__ __launch_bounds__(256) void cvt_swz(const float* __restrict__ src,
                                               bf16* __restrict__ dst,
                                               int total, int cols) {
  int idx = blockIdx.x * 256 + threadIdx.x;
  if (idx >= total) return;
  int r = idx / cols, c = idx - r * cols;
  int seg = c >> 6, cl = c & 63;
  int ch = (cl >> 3) ^ (r & 7);
  dst[(size_t)r * cols + (seg << 6) + (ch << 3) + (cl & 7)] = (bf16)src[idx];
}

__global__ void bias_cat(const float* __restrict__ qb, const float* __restrict__ kb,
                         const float* __restrict__ vb, float* __restrict__ out) {
  int i = blockIdx.x * 256 + threadIdx.x;
  if (i >= 3072) return;
  out[i] = (i < 1024) ? qb[i] : (i < 2048 ? kb[i - 1024] : vb[i - 2048]);
}

// ---------------- P3: RoPE cos/sin table [2048][32] ------------------------
__global__ void rope_tab(float* __restrict__ ct, float* __restrict__ st) {
  int idx = blockIdx.x * 256 + threadIdx.x;
  if (idx >= SEQ * 32) return;
  int s = idx >> 5, i = idx & 31;
  double inv = pow(1.0e6, -(double)i / 32.0);
  double a = (double)s * inv;
  ct[idx] = (float)cos(a);
  st[idx] = (float)sin(a);
}

// ---------------- K1/K5: bf16 MFMA GEMM, C = A @ Bw^T (+bias) --------------
__global__ __launch_bounds__(256) void gemm_bt(
    const bf16* __restrict__ A, const bf16* __restrict__ Bw,
    const float* __restrict__ bias, bf16* __restrict__ Cb,
    float* __restrict__ Cf, int M, int N, int K) {
  __shared__ __align__(16) bf16 As[128 * 64];
  __shared__ __align__(16) bf16 Bs[128 * 64];
  const int tid = threadIdx.x;
  const int lane = tid & 63, w = tid >> 6;
  const int wm = w >> 1, wn = w & 1;
  const int l15 = lane & 15, l4 = lane >> 4;
  const int m0 = blockIdx.y * 128, n0 = blockIdx.x * 128;
  const size_t rowb = (size_t)K * 2;
  const char* gA = (const char*)A + (size_t)m0 * rowb;
  const char* gB = (const char*)Bw + (size_t)n0 * rowb;
  f32x4 acc[4][4] = {};

  for (int k0 = 0; k0 < K; k0 += 64) {
    const char* gAk = gA + k0 * 2;
    const char* gBk = gB + k0 * 2;
#pragma unroll
    for (int i = 0; i < 4; ++i) {
      int idx = i * 256 + tid;
      int row = idx >> 3, ch = idx & 7;
      gld_lds16(gAk + (size_t)row * rowb + ch * 16,
                (char*)As + (i * 256 + (w << 6)) * 16);
      gld_lds16(gBk + (size_t)row * rowb + ch * 16,
                (char*)Bs + (i * 256 + (w << 6)) * 16);
    }
    __syncthreads();
#pragma unroll
    for (int c = 0; c < 2; ++c) {
      bf16x8 af[4], bfr[4];
#pragma unroll
      for (int mi = 0; mi < 4; ++mi) {
        int row = wm * 64 + mi * 16 + l15;
        int ch = (c * 4 + l4) ^ (row & 7);
        af[mi] = *(const bf16x8*)(As + row * 64 + ch * 8);
      }
#pragma unroll
      for (int ni = 0; ni < 4; ++ni) {
        int row = wn * 64 + ni * 16 + l15;
        int ch = (c * 4 + l4) ^ (row & 7);
        bfr[ni] = *(const bf16x8*)(Bs + row * 64 + ch * 8);
      }
#pragma unroll
      for (int mi = 0; mi < 4; ++mi)
#pragma unroll
        for (int ni = 0; ni < 4; ++ni)
          acc[mi][ni] = __builtin_amdgcn_mfma_f32_16x16x32_bf16(
              af[mi], bfr[ni], acc[mi][ni], 0, 0, 0);
    }
    __syncthreads();
  }
#pragma unroll
  for (int mi = 0; mi < 4; ++mi) {
    int rbase = m0 + wm * 64 + mi * 16 + l4 * 4;
#pragma unroll
    for (int ni = 0; ni < 4; ++ni) {
      int col = n0 + wn * 64 + ni * 16 + l15;
      float badd = bias ? bias[col] : 0.0f;
#pragma unroll
      for (int r = 0; r < 4; ++r) {
        float v = acc[mi][ni][r] + badd;
        if (Cf) Cf[(size_t)(rbase + r) * N + col] = v;
        else    Cb[(size_t)(rbase + r) * N + col] = (bf16)v;
      }
    }
  }
}

// ---------------- K2: RoPE on q -> Qr [B,NH,S,HD] (plain) ------------------
__global__ __launch_bounds__(256) void rope_q(
    const bf16* __restrict__ qkv, const int* __restrict__ pos,
    const float* __restrict__ ct, const float* __restrict__ st,
    bf16* __restrict__ Qr) {
  int idx = blockIdx.x * 256 + threadIdx.x;  // [b][s][h][i]
  if (idx >= NB * NHD * SEQ * 32) return;
  int i = idx & 31, h = (idx >> 5) & 15, s = (idx >> 9) & 2047, b = idx >> 20;
  int p = pos[b * SEQ + s];
  float co = ct[p * 32 + i], sn = st[p * 32 + i];
  size_t base = ((size_t)(b * SEQ + s)) * 3072 + h * 64 + i;
  float x = (float)qkv[base], y = (float)qkv[base + 32];
  size_t ob = ((size_t)((b * 16 + h) * SEQ + s)) * 64 + i;
  Qr[ob]      = (bf16)(x * co - y * sn);
  Qr[ob + 32] = (bf16)(y * co + x * sn);
}

// ---------------- K3: RoPE(k) + holographic bind/sum -----------------------
__global__ __launch_bounds__(256) void holo_kv(
    const bf16* __restrict__ qkv, const int* __restrict__ pos,
    const float* __restrict__ ct, const float* __restrict__ st,
    const float* __restrict__ cdma, bf16* __restrict__ Kn,
    bf16* __restrict__ Vt) {
  int idx = blockIdx.x * 256 + threadIdx.x;  // [b][h][slot][i]
  if (idx >= NB * NHD * (SEQ / 4) * 32) return;
  int i = idx & 31, slot = (idx >> 5) & 511, h = (idx >> 14) & 15, b = idx >> 18;
  float c[4];
  float SK = 0.f, SK2 = 0.f, SV = 0.f, SV2 = 0.f;
#pragma unroll
  for (int f = 0; f < 4; ++f) {
    int s = slot * 4 + f;
    float cf = cdma[f * 64 + i];
    c[f] = cf;
    size_t base = ((size_t)(b * SEQ + s)) * 3072 + h * 64 + i;
    float kx = (float)qkv[base + 1024], ky = (float)qkv[base + 1024 + 32];
    int p = pos[b * SEQ + s];
    float co = ct[p * 32 + i], sn = st[p * 32 + i];
    SK  += (kx * co - ky * sn) * cf;
    SK2 += (ky * co + kx * sn) * cf;
    SV  += (float)qkv[base + 2048] * cf;
    SV2 += (float)qkv[base + 2048 + 32] * cf;
  }
  size_t hb = (size_t)(b * 16 + h);
#pragma unroll
  for (int f = 0; f < 4; ++f) {
    int s = slot * 4 + f;
    size_t krow = (hb * SEQ + s) * 64;
    int ch0 = (i >> 3) ^ (s & 7);
    int ch1 = (4 + (i >> 3)) ^ (s & 7);
    Kn[krow + ch0 * 8 + (i & 7)] = (bf16)(SK * c[f]);
    Kn[krow + ch1 * 8 + (i & 7)] = (bf16)(SK2 * c[f]);
    int seg = s >> 6, cl = s & 63;
    int vch = (cl >> 3) ^ (i & 7);
    size_t vrow0 = (hb * 64 + i) * (size_t)SEQ + (seg << 6);
    size_t vrow1 = (hb * 64 + i + 32) * (size_t)SEQ + (seg << 6);
    Vt[vrow0 + vch * 8 + (cl & 7)] = (bf16)(SV * c[f]);
    Vt[vrow1 + vch * 8 + (cl & 7)] = (bf16)(SV2 * c[f]);
  }
}

// ---------------- K4: causal flash attention (R5) --------------------------
// grid (32 LPT-ordered q-tiles, h=16, b=2), 4 waves x 16 q-rows.
// qt = 31 - bx  => largest tiles dispatch first (LPT packing).
// Swapped QK^T AND swapped PV: softmax stats and O^T[d][q=l15] in-lane.
__global__ __launch_bounds__(256) void attn_fwd(
    const bf16* __restrict__ Qr, const bf16* __restrict__ Kn,
    const bf16* __restrict__ Vt, bf16* __restrict__ AO) {
  __shared__ __align__(16) bf16 Kt[2][64 * 64];
  __shared__ __align__(16) bf16 Vl[2][64 * 64];
  __shared__ __align__(16) bf16 Pt[4][16 * 64];
  const int qt = 31 - blockIdx.x, h = blockIdx.y, b = blockIdx.z;
  const int tid = threadIdx.x, lane = tid & 63, w = tid >> 6;
  const int l15 = lane & 15, l4 = lane >> 4;
  const int q0 = qt * 64;
  const int qg = q0 + w * 16 + l15;  // this lane's q row (softmax/O col)
  const int nt = qt + 1;
  const size_t hd = ((size_t)(b * 16 + h)) * SEQ * 64;
  const char* gK0 = (const char*)(Kn + hd);
  const char* gV0 = (const char*)(Vt + hd);
  char* pw = (char*)&Pt[w][0];
  const float sc = (1.0f / 16.0f) * 1.44269504f;  // scale * log2(e)

  const bf16* qb = Qr + hd + (size_t)qg * 64;
  bf16x8 qf0 = *(const bf16x8*)(qb + l4 * 8);
  bf16x8 qf1 = *(const bf16x8*)(qb + 32 + l4 * 8);

  f32x4 oacc[4] = {};          // O^T: d = df*16 + l4*4 + r, q = l15
  float m = -1e30f, lsum = 0.0f;

  // prologue: stage tile 0 into buf 0
#pragma unroll
  for (int i = 0; i < 2; ++i) {
    int idx = i * 256 + tid;
    int row = idx >> 3, ch = idx & 7;
    gld_lds16(gK0 + (size_t)row * 128 + ch * 16,
              (char*)Kt[0] + (i * 256 + (w << 6)) * 16);
    gld_lds16(gV0 + (size_t)row * (SEQ * 2) + ch * 16,
              (char*)Vl[0] + (i * 256 + (w << 6)) * 16);
  }

#pragma unroll 1
  for (int t = 0; t < nt; ++t) {
    const int cur = t & 1;
    if (t + 1 < nt) {
      const int tn = t + 1, s = cur ^ 1;
#pragma unroll
      for (int i = 0; i < 2; ++i) {
        int idx = i * 256 + tid;
        int row = idx >> 3, ch = idx & 7;
        gld_lds16(gK0 + (size_t)(tn * 64 + row) * 128 + ch * 16,
                  (char*)Kt[s] + (i * 256 + (w << 6)) * 16);
        gld_lds16(gV0 + (size_t)row * (SEQ * 2) + tn * 128 + ch * 16,
                  (char*)Vl[s] + (i * 256 + (w << 6)) * 16);
      }
      asm volatile("s_waitcnt vmcnt(4)\ns_barrier" ::: "memory");
    } else {
      asm volatile("s_waitcnt vmcnt(0)\ns_barrier" ::: "memory");
    }

    const bf16* Ktc = Kt[cur];
    const bf16* Vlc = Vl[cur];
    const int kv0 = t * 64;
    const bool diag = (t == qt);

    // QK^T swapped: sacc = K·Q^T ; col=l15=q, kv = nf*16 + l4*4 + r
    f32x4 sacc[4] = {};
    __builtin_amdgcn_s_setprio(1);
#pragma unroll
    for (int c = 0; c < 2; ++c) {
      bf16x8 qf = c ? qf1 : qf0;
#pragma unroll
      for (int nf = 0; nf < 4; ++nf) {
        int row = nf * 16 + l15;
        int ch = (c * 4 + l4) ^ (row & 7);
        bf16x8 kf = *(const bf16x8*)(Ktc + row * 64 + ch * 8);
        sacc[nf] = __builtin_amdgcn_mfma_f32_16x16x32_bf16(kf, qf, sacc[nf], 0, 0, 0);
      }
    }
    __builtin_amdgcn_s_setprio(0);

    // scale + causal mask + in-lane max
    float pmax = -1e30f;
#pragma unroll
    for (int nf = 0; nf < 4; ++nf)
#pragma unroll
      for (int r = 0; r < 4; ++r) {
        float v = sacc[nf][r] * sc;
        if (diag) {
          int kvg = kv0 + nf * 16 + l4 * 4 + r;
          if (kvg > qg) v = -1e30f;
        }
        sacc[nf][r] = v;
        pmax = fmaxf(pmax, v);
      }
    pmax = fmaxf(pmax, __shfl_xor(pmax, 16));
    pmax = fmaxf(pmax, __shfl_xor(pmax, 32));

    // online stats; exact skip when no row's max grew
    if (!__all(pmax <= m)) {
      float mn = fmaxf(m, pmax);
      float al = exp2f(m - mn);
      m = mn;
      lsum *= al;
#pragma unroll
      for (int df = 0; df < 4; ++df) oacc[df] *= al;
    }
    float rs = 0.0f;
#pragma unroll
    for (int nf = 0; nf < 4; ++nf)
#pragma unroll
      for (int r = 0; r < 4; ++r) {
        float e = exp2f(sacc[nf][r] - m);
        sacc[nf][r] = e;
        rs += e;
      }
    rs += __shfl_xor(rs, 16);
    rs += __shfl_xor(rs, 32);
    lsum += rs;

    // P (q=l15, kv=nf*16+l4*4+r) -> swizzled wave-private LDS, packed b32
#pragma unroll
    for (int nf = 0; nf < 4; ++nf)
#pragma unroll
      for (int rp = 0; rp < 2; ++rp) {
        unsigned u = pack2bf(sacc[nf][rp * 2], sacc[nf][rp * 2 + 1]);
        int boff = l15 * 128 + (nf * 16 + l4 * 4 + rp * 2) * 2;
        boff ^= (l15 & 7) << 4;
        *(unsigned*)(pw + boff) = u;
      }

    // PV swapped: oacc = V^T·P^T  (A-side = V^T rows d, B-side = P cols q)
    __builtin_amdgcn_s_setprio(1);
#pragma unroll
    for (int c = 0; c < 2; ++c) {
      int pb = (l15 * 128 + c * 64 + l4 * 16) ^ ((l15 & 7) << 4);
      bf16x8 pf = *(const bf16x8*)(pw + pb);
#pragma unroll
      for (int df = 0; df < 4; ++df) {
        int vrow = df * 16 + l15;
        int vch = (c * 4 + l4) ^ (vrow & 7);
        bf16x8 vf = *(const bf16x8*)(Vlc + vrow * 64 + vch * 8);
        oacc[df] = __builtin_amdgcn_mfma_f32_16x16x32_bf16(vf, pf, oacc[df], 0, 0, 0);
      }
    }
    __builtin_amdgcn_s_setprio(0);
    asm volatile("s_barrier" ::: "memory");
  }

  // epilogue: O^T[d][q=l15] -> AO[q][h*64+d] (preswizzled for K5, key q&7)
  const float li = 1.0f / lsum;
  const size_t arow = ((size_t)(b * SEQ + qg)) * HID + h * 64;
  const int qk7 = qg & 7;
#pragma unroll
  for (int df = 0; df < 4; ++df)
#pragma unroll
    for (int r = 0; r < 4; ++r) {
      int d = df * 16 + l4 * 4 + r;
      int ch = (d >> 3) ^ qk7;
      AO[arow + ch * 8 + (d & 7)] = (bf16)(oacc[df][r] * li);
    }
}

// ---------------------------------------------------------------------------
extern "C" void kernel_launch(void* const* d_in, const int* in_sizes, int n_in,
                              void* d_out, int out_size, void* d_ws, size_t ws_size,
                              hipStream_t stream) {
  const float* hs  = (const float*)d_in[0];
  const int* pos   = (const int*)d_in[1];
  const float* qw  = (const float*)d_in[2];
  const float* qb_ = (const float*)d_in[3];
  const float* kw  = (const float*)d_in[4];
  const float* kb_ = (const float*)d_in[5];
  const float* vw  = (const float*)d_in[6];
  const float* vb_ = (const float*)d_in[7];
  const float* ow  = (const float*)d_in[8];
  const float* qA  = (const float*)d_in[9];
  const float* qB  = (const float*)d_in[10];
  const float* vA  = (const float*)d_in[11];
  const float* vB  = (const float*)d_in[12];
  const float* cd  = (const float*)d_in[13];

  char* p = (char*)d_ws;
  auto alloc = [&](size_t bytes) {
    char* r = p; p += (bytes + 255) & ~(size_t)255; return r;
  };
  bf16* hsb   = (bf16*)alloc((size_t)4096 * 1024 * 2);
  bf16* Wqkv  = (bf16*)alloc((size_t)3072 * 1024 * 2);
  float* bqkv = (float*)alloc(3072 * 4);
  bf16* owb   = (bf16*)alloc((size_t)1024 * 1024 * 2);
  bf16* qkvb  = (bf16*)alloc((size_t)4096 * 3072 * 2);
  float* ct   = (float*)alloc((size_t)SEQ * 32 * 4);
  float* st   = (float*)alloc((size_t)SEQ * 32 * 4);
  bf16* Qrb   = (bf16*)alloc((size_t)NB * NHD * SEQ * 64 * 2);
  bf16* Knb   = (bf16*)alloc((size_t)NB * NHD * SEQ * 64 * 2);
  bf16* Vtb   = (bf16*)alloc((size_t)NB * NHD * 64 * SEQ * 2);
  bf16* AOb   = (bf16*)alloc((size_t)4096 * 1024 * 2);

  prep_wqkv<<<dim3(3072 * 1024 / 256), 256, 0, stream>>>(qw, kw, vw, qA, qB, vA, vB, Wqkv);
  cvt_swz<<<dim3(4096 * 1024 / 256), 256, 0, stream>>>(hs, hsb, 4096 * 1024, 1024);
  cvt_swz<<<dim3(1024 * 1024 / 256), 256, 0, stream>>>(ow, owb, 1024 * 1024, 1024);
  bias_cat<<<dim3(12), 256, 0, stream>>>(qb_, kb_, vb_, bqkv);
  rope_tab<<<dim3(SEQ * 32 / 256), 256, 0, stream>>>(ct, st);
  gemm_bt<<<dim3(3072 / 128, 4096 / 128), 256, 0, stream>>>(
      hsb, Wqkv, bqkv, qkvb, nullptr, 4096, 3072, 1024);
  rope_q<<<dim3(NB * NHD * SEQ * 32 / 256), 256, 0, stream>>>(qkvb, pos, ct, st, Qrb);
  holo_kv<<<dim3(NB * NHD * (SEQ / 4) * 32 / 256), 256, 0, stream>>>(
      qkvb, pos, ct, st, cd, Knb, Vtb);
  attn_fwd<<<dim3(32, NHD, NB), 256, 0, stream>>>(Qrb, Knb, Vtb, AOb);
  gemm_bt<<<dim3(1024 / 128, 4096 / 128), 256, 0, stream>>>(
      AOb, owb, nullptr, nullptr, (float*)d_out, 4096, 1024, 1024);
}

// Round 8
// 176.311 us; speedup vs baseline: 1.1491x; 1.1491x over previous
//
#include <hip/hip_runtime.h>
#include <hip/hip_bf16.h>
#include <math.h>

// ---------------------------------------------------------------------------
// HoloKVSimulatorLayer fused pipeline, bf16 MFMA, MI355X (gfx950)
//   B=2 S=2048 H=1024 NH=NKV=16 HD=64 R=16 KF=4 theta=1e6
// R8: attn_fwd = R4's paired schedule (512 blocks, 2/CU, 33 steps, balanced)
// + R5's swapped-PV in-lane stats + exact rescale-skip. No setprio, no LPT.
// ---------------------------------------------------------------------------

typedef __bf16 bf16;
typedef __attribute__((ext_vector_type(8))) __bf16 bf16x8;
typedef __attribute__((ext_vector_type(4))) float f32x4;

#define NB 2
#define SEQ 2048
#define HID 1024
#define NHD 16
#define HDD 64

__device__ __forceinline__ void gld_lds16(const void* g, void* l) {
  __builtin_amdgcn_global_load_lds(
      (const __attribute__((address_space(1))) void*)g,
      (__attribute__((address_space(3))) void*)l, 16, 0, 0);
}

__device__ __forceinline__ unsigned pack2bf(float a, float b) {
  unsigned short ua = __builtin_bit_cast(unsigned short, (bf16)a);
  unsigned short ub = __builtin_bit_cast(unsigned short, (bf16)b);
  return ((unsigned)ub << 16) | ua;
}

// ---------------- P0: fold LoRA into weights, swizzle, bf16 ----------------
__global__ __launch_bounds__(256) void prep_wqkv(
    const float* __restrict__ qw, const float* __restrict__ kw,
    const float* __restrict__ vw, const float* __restrict__ qA,
    const float* __restrict__ qB, const float* __restrict__ vA,
    const float* __restrict__ vB, bf16* __restrict__ W) {
  int idx = blockIdx.x * 256 + threadIdx.x;   // n*1024 + k, n in [0,3072)
  if (idx >= 3072 * 1024) return;
  int n = idx >> 10, k = idx & 1023;
  float v;
  if (n < 1024) {
    v = qw[n * 1024 + k];
#pragma unroll
    for (int r = 0; r < 16; ++r) v += qB[n * 16 + r] * qA[r * 1024 + k];
  } else if (n < 2048) {
    v = kw[(n - 1024) * 1024 + k];
  } else {
    int nn = n - 2048;
    v = vw[nn * 1024 + k];
#pragma unroll
    for (int r = 0; r < 16; ++r) v += vB[nn * 16 + r] * vA[r * 1024 + k];
  }
  int seg = k >> 6, cl = k & 63;
  int ch = (cl >> 3) ^ (n & 7);
  W[(size_t)n * 1024 + (seg << 6) + (ch << 3) + (cl & 7)] = (bf16)v;
}

// ---------------- P1: f32 -> bf16 with global pre-swizzle ------------------
__global__ __launch_bounds__(256) void cvt_swz(const float* __restrict__ src,
                                               bf16* __restrict__ dst,
                                               int total, int cols) {
  int idx = blockIdx.x * 256 + threadIdx.x;
  if (idx >= total) return;
  int r = idx / cols, c = idx - r * cols;
  int seg = c >> 6, cl = c & 63;
  int ch = (cl >> 3) ^ (r & 7);
  dst[(size_t)r * cols + (seg << 6) + (ch << 3) + (cl & 7)] = (bf16)src[idx];
}

__global__ void bias_cat(const float* __restrict__ qb, const float* __restrict__ kb,
                         const float* __restrict__ vb, float* __restrict__ out) {
  int i = blockIdx.x * 256 + threadIdx.x;
  if (i >= 3072) return;
  out[i] = (i < 1024) ? qb[i] : (i < 2048 ? kb[i - 1024] : vb[i - 2048]);
}

// ---------------- P3: RoPE cos/sin table [2048][32] ------------------------
__global__ void rope_tab(float* __restrict__ ct, float* __restrict__ st) {
  int idx = blockIdx.x * 256 + threadIdx.x;
  if (idx >= SEQ * 32) return;
  int s = idx >> 5, i = idx & 31;
  double inv = pow(1.0e6, -(double)i / 32.0);
  double a = (double)s * inv;
  ct[idx] = (float)cos(a);
  st[idx] = (float)sin(a);
}

// ---------------- K1/K5: bf16 MFMA GEMM, C = A @ Bw^T (+bias) --------------
__global__ __launch_bounds__(256) void gemm_bt(
    const bf16* __restrict__ A, const bf16* __restrict__ Bw,
    const float* __restrict__ bias, bf16* __restrict__ Cb,
    float* __restrict__ Cf, int M, int N, int K) {
  __shared__ __align__(16) bf16 As[128 * 64];
  __shared__ __align__(16) bf16 Bs[128 * 64];
  const int tid = threadIdx.x;
  const int lane = tid & 63, w = tid >> 6;
  const int wm = w >> 1, wn = w & 1;
  const int l15 = lane & 15, l4 = lane >> 4;
  const int m0 = blockIdx.y * 128, n0 = blockIdx.x * 128;
  const size_t rowb = (size_t)K * 2;
  const char* gA = (const char*)A + (size_t)m0 * rowb;
  const char* gB = (const char*)Bw + (size_t)n0 * rowb;
  f32x4 acc[4][4] = {};

  for (int k0 = 0; k0 < K; k0 += 64) {
    const char* gAk = gA + k0 * 2;
    const char* gBk = gB + k0 * 2;
#pragma unroll
    for (int i = 0; i < 4; ++i) {
      int idx = i * 256 + tid;
      int row = idx >> 3, ch = idx & 7;
      gld_lds16(gAk + (size_t)row * rowb + ch * 16,
                (char*)As + (i * 256 + (w << 6)) * 16);
      gld_lds16(gBk + (size_t)row * rowb + ch * 16,
                (char*)Bs + (i * 256 + (w << 6)) * 16);
    }
    __syncthreads();
#pragma unroll
    for (int c = 0; c < 2; ++c) {
      bf16x8 af[4], bfr[4];
#pragma unroll
      for (int mi = 0; mi < 4; ++mi) {
        int row = wm * 64 + mi * 16 + l15;
        int ch = (c * 4 + l4) ^ (row & 7);
        af[mi] = *(const bf16x8*)(As + row * 64 + ch * 8);
      }
#pragma unroll
      for (int ni = 0; ni < 4; ++ni) {
        int row = wn * 64 + ni * 16 + l15;
        int ch = (c * 4 + l4) ^ (row & 7);
        bfr[ni] = *(const bf16x8*)(Bs + row * 64 + ch * 8);
      }
#pragma unroll
      for (int mi = 0; mi < 4; ++mi)
#pragma unroll
        for (int ni = 0; ni < 4; ++ni)
          acc[mi][ni] = __builtin_amdgcn_mfma_f32_16x16x32_bf16(
              af[mi], bfr[ni], acc[mi][ni], 0, 0, 0);
    }
    __syncthreads();
  }
#pragma unroll
  for (int mi = 0; mi < 4; ++mi) {
    int rbase = m0 + wm * 64 + mi * 16 + l4 * 4;
#pragma unroll
    for (int ni = 0; ni < 4; ++ni) {
      int col = n0 + wn * 64 + ni * 16 + l15;
      float badd = bias ? bias[col] : 0.0f;
#pragma unroll
      for (int r = 0; r < 4; ++r) {
        float v = acc[mi][ni][r] + badd;
        if (Cf) Cf[(size_t)(rbase + r) * N + col] = v;
        else    Cb[(size_t)(rbase + r) * N + col] = (bf16)v;
      }
    }
  }
}

// ---------------- K2: RoPE on q -> Qr [B,NH,S,HD] (plain) ------------------
__global__ __launch_bounds__(256) void rope_q(
    const bf16* __restrict__ qkv, const int* __restrict__ pos,
    const float* __restrict__ ct, const float* __restrict__ st,
    bf16* __restrict__ Qr) {
  int idx = blockIdx.x * 256 + threadIdx.x;  // [b][s][h][i]
  if (idx >= NB * NHD * SEQ * 32) return;
  int i = idx & 31, h = (idx >> 5) & 15, s = (idx >> 9) & 2047, b = idx >> 20;
  int p = pos[b * SEQ + s];
  float co = ct[p * 32 + i], sn = st[p * 32 + i];
  size_t base = ((size_t)(b * SEQ + s)) * 3072 + h * 64 + i;
  float x = (float)qkv[base], y = (float)qkv[base + 32];
  size_t ob = ((size_t)((b * 16 + h) * SEQ + s)) * 64 + i;
  Qr[ob]      = (bf16)(x * co - y * sn);
  Qr[ob + 32] = (bf16)(y * co + x * sn);
}

// ---------------- K3: RoPE(k) + holographic bind/sum -----------------------
__global__ __launch_bounds__(256) void holo_kv(
    const bf16* __restrict__ qkv, const int* __restrict__ pos,
    const float* __restrict__ ct, const float* __restrict__ st,
    const float* __restrict__ cdma, bf16* __restrict__ Kn,
    bf16* __restrict__ Vt) {
  int idx = blockIdx.x * 256 + threadIdx.x;  // [b][h][slot][i]
  if (idx >= NB * NHD * (SEQ / 4) * 32) return;
  int i = idx & 31, slot = (idx >> 5) & 511, h = (idx >> 14) & 15, b = idx >> 18;
  float c[4];
  float SK = 0.f, SK2 = 0.f, SV = 0.f, SV2 = 0.f;
#pragma unroll
  for (int f = 0; f < 4; ++f) {
    int s = slot * 4 + f;
    float cf = cdma[f * 64 + i];
    c[f] = cf;
    size_t base = ((size_t)(b * SEQ + s)) * 3072 + h * 64 + i;
    float kx = (float)qkv[base + 1024], ky = (float)qkv[base + 1024 + 32];
    int p = pos[b * SEQ + s];
    float co = ct[p * 32 + i], sn = st[p * 32 + i];
    SK  += (kx * co - ky * sn) * cf;
    SK2 += (ky * co + kx * sn) * cf;
    SV  += (float)qkv[base + 2048] * cf;
    SV2 += (float)qkv[base + 2048 + 32] * cf;
  }
  size_t hb = (size_t)(b * 16 + h);
#pragma unroll
  for (int f = 0; f < 4; ++f) {
    int s = slot * 4 + f;
    size_t krow = (hb * SEQ + s) * 64;
    int ch0 = (i >> 3) ^ (s & 7);
    int ch1 = (4 + (i >> 3)) ^ (s & 7);
    Kn[krow + ch0 * 8 + (i & 7)] = (bf16)(SK * c[f]);
    Kn[krow + ch1 * 8 + (i & 7)] = (bf16)(SK2 * c[f]);
    int seg = s >> 6, cl = s & 63;
    int vch = (cl >> 3) ^ (i & 7);
    size_t vrow0 = (hb * 64 + i) * (size_t)SEQ + (seg << 6);
    size_t vrow1 = (hb * 64 + i + 32) * (size_t)SEQ + (seg << 6);
    Vt[vrow0 + vch * 8 + (cl & 7)] = (bf16)(SV * c[f]);
    Vt[vrow1 + vch * 8 + (cl & 7)] = (bf16)(SV2 * c[f]);
  }
}

// ---------------- K4: causal flash attention (R8) --------------------------
// grid (16 pairs, h=16, b=2); block does q-tiles {pq, 31-pq} = 33 steps.
// K/V dbuf + counted vmcnt. Swapped QK^T AND swapped PV: stats + O^T in-lane.
__global__ __launch_bounds__(256) void attn_fwd(
    const bf16* __restrict__ Qr, const bf16* __restrict__ Kn,
    const bf16* __restrict__ Vt, bf16* __restrict__ AO) {
  __shared__ __align__(16) bf16 Kt[2][64 * 64];
  __shared__ __align__(16) bf16 Vl[2][64 * 64];
  __shared__ __align__(16) bf16 Pt[4][16 * 64];
  const int pq = blockIdx.x, h = blockIdx.y, b = blockIdx.z;
  const int tid = threadIdx.x, lane = tid & 63, w = tid >> 6;
  const int l15 = lane & 15, l4 = lane >> 4;
  const size_t hd = ((size_t)(b * 16 + h)) * SEQ * 64;
  const char* gK0 = (const char*)(Kn + hd);
  const char* gV0 = (const char*)(Vt + hd);
  char* pw = (char*)&Pt[w][0];
  const float sc = (1.0f / 16.0f) * 1.44269504f;  // scale * log2(e)

#pragma unroll 1
  for (int phase = 0; phase < 2; ++phase) {
    const int qt = phase ? (31 - pq) : pq;
    const int q0 = qt * 64;
    const int qg = q0 + w * 16 + l15;  // this lane's q row (softmax/O col)
    const int nt = qt + 1;

    const bf16* qb = Qr + hd + (size_t)qg * 64;
    bf16x8 qf0 = *(const bf16x8*)(qb + l4 * 8);
    bf16x8 qf1 = *(const bf16x8*)(qb + 32 + l4 * 8);

    f32x4 oacc[4] = {};        // O^T: d = df*16 + l4*4 + r, q = l15
    float m = -1e30f, lsum = 0.0f;

    // prologue: stage tile 0 into buf 0
#pragma unroll
    for (int i = 0; i < 2; ++i) {
      int idx = i * 256 + tid;
      int row = idx >> 3, ch = idx & 7;
      gld_lds16(gK0 + (size_t)row * 128 + ch * 16,
                (char*)Kt[0] + (i * 256 + (w << 6)) * 16);
      gld_lds16(gV0 + (size_t)row * (SEQ * 2) + ch * 16,
                (char*)Vl[0] + (i * 256 + (w << 6)) * 16);
    }

#pragma unroll 1
    for (int t = 0; t < nt; ++t) {
      const int cur = t & 1;
      if (t + 1 < nt) {
        const int tn = t + 1, s = cur ^ 1;
#pragma unroll
        for (int i = 0; i < 2; ++i) {
          int idx = i * 256 + tid;
          int row = idx >> 3, ch = idx & 7;
          gld_lds16(gK0 + (size_t)(tn * 64 + row) * 128 + ch * 16,
                    (char*)Kt[s] + (i * 256 + (w << 6)) * 16);
          gld_lds16(gV0 + (size_t)row * (SEQ * 2) + tn * 128 + ch * 16,
                    (char*)Vl[s] + (i * 256 + (w << 6)) * 16);
        }
        asm volatile("s_waitcnt vmcnt(4)\ns_barrier" ::: "memory");
      } else {
        asm volatile("s_waitcnt vmcnt(0)\ns_barrier" ::: "memory");
      }

      const bf16* Ktc = Kt[cur];
      const bf16* Vlc = Vl[cur];
      const int kv0 = t * 64;
      const bool diag = (t == qt);

      // QK^T swapped: sacc = K·Q^T ; col=l15=q, kv = nf*16 + l4*4 + r
      f32x4 sacc[4] = {};
#pragma unroll
      for (int c = 0; c < 2; ++c) {
        bf16x8 qf = c ? qf1 : qf0;
#pragma unroll
        for (int nf = 0; nf < 4; ++nf) {
          int row = nf * 16 + l15;
          int ch = (c * 4 + l4) ^ (row & 7);
          bf16x8 kf = *(const bf16x8*)(Ktc + row * 64 + ch * 8);
          sacc[nf] = __builtin_amdgcn_mfma_f32_16x16x32_bf16(kf, qf, sacc[nf], 0, 0, 0);
        }
      }

      // scale + causal mask + in-lane max
      float pmax = -1e30f;
#pragma unroll
      for (int nf = 0; nf < 4; ++nf)
#pragma unroll
        for (int r = 0; r < 4; ++r) {
          float v = sacc[nf][r] * sc;
          if (diag) {
            int kvg = kv0 + nf * 16 + l4 * 4 + r;
            if (kvg > qg) v = -1e30f;
          }
          sacc[nf][r] = v;
          pmax = fmaxf(pmax, v);
        }
      pmax = fmaxf(pmax, __shfl_xor(pmax, 16));
      pmax = fmaxf(pmax, __shfl_xor(pmax, 32));

      // online stats; exact skip when no row's max grew
      if (!__all(pmax <= m)) {
        float mn = fmaxf(m, pmax);
        float al = exp2f(m - mn);
        m = mn;
        lsum *= al;
#pragma unroll
        for (int df = 0; df < 4; ++df) oacc[df] *= al;
      }
      float rs = 0.0f;
#pragma unroll
      for (int nf = 0; nf < 4; ++nf)
#pragma unroll
        for (int r = 0; r < 4; ++r) {
          float e = exp2f(sacc[nf][r] - m);
          sacc[nf][r] = e;
          rs += e;
        }
      rs += __shfl_xor(rs, 16);
      rs += __shfl_xor(rs, 32);
      lsum += rs;

      // P (q=l15, kv=nf*16+l4*4+r) -> swizzled wave-private LDS, packed b32
#pragma unroll
      for (int nf = 0; nf < 4; ++nf)
#pragma unroll
        for (int rp = 0; rp < 2; ++rp) {
          unsigned u = pack2bf(sacc[nf][rp * 2], sacc[nf][rp * 2 + 1]);
          int boff = l15 * 128 + (nf * 16 + l4 * 4 + rp * 2) * 2;
          boff ^= (l15 & 7) << 4;
          *(unsigned*)(pw + boff) = u;
        }

      // PV swapped: oacc = V^T·P^T  (A-side = V^T rows d, B-side = P cols q)
#pragma unroll
      for (int c = 0; c < 2; ++c) {
        int pb = (l15 * 128 + c * 64 + l4 * 16) ^ ((l15 & 7) << 4);
        bf16x8 pf = *(const bf16x8*)(pw + pb);
#pragma unroll
        for (int df = 0; df < 4; ++df) {
          int vrow = df * 16 + l15;
          int vch = (c * 4 + l4) ^ (vrow & 7);
          bf16x8 vf = *(const bf16x8*)(Vlc + vrow * 64 + vch * 8);
          oacc[df] = __builtin_amdgcn_mfma_f32_16x16x32_bf16(vf, pf, oacc[df], 0, 0, 0);
        }
      }
      asm volatile("s_barrier" ::: "memory");
    }

    // epilogue: O^T[d][q=l15] -> AO[q][h*64+d] (preswizzled for K5, key q&7)
    const float li = 1.0f / lsum;
    const size_t arow = ((size_t)(b * SEQ + qg)) * HID + h * 64;
    const int qk7 = qg & 7;
#pragma unroll
    for (int df = 0; df < 4; ++df)
#pragma unroll
      for (int r = 0; r < 4; ++r) {
        int d = df * 16 + l4 * 4 + r;
        int ch = (d >> 3) ^ qk7;
        AO[arow + ch * 8 + (d & 7)] = (bf16)(oacc[df][r] * li);
      }
  }
}

// ---------------------------------------------------------------------------
extern "C" void kernel_launch(void* const* d_in, const int* in_sizes, int n_in,
                              void* d_out, int out_size, void* d_ws, size_t ws_size,
                              hipStream_t stream) {
  const float* hs  = (const float*)d_in[0];
  const int* pos   = (const int*)d_in[1];
  const float* qw  = (const float*)d_in[2];
  const float* qb_ = (const float*)d_in[3];
  const float* kw  = (const float*)d_in[4];
  const float* kb_ = (const float*)d_in[5];
  const float* vw  = (const float*)d_in[6];
  const float* vb_ = (const float*)d_in[7];
  const float* ow  = (const float*)d_in[8];
  const float* qA  = (const float*)d_in[9];
  const float* qB  = (const float*)d_in[10];
  const float* vA  = (const float*)d_in[11];
  const float* vB  = (const float*)d_in[12];
  const float* cd  = (const float*)d_in[13];

  char* p = (char*)d_ws;
  auto alloc = [&](size_t bytes) {
    char* r = p; p += (bytes + 255) & ~(size_t)255; return r;
  };
  bf16* hsb   = (bf16*)alloc((size_t)4096 * 1024 * 2);
  bf16* Wqkv  = (bf16*)alloc((size_t)3072 * 1024 * 2);
  float* bqkv = (float*)alloc(3072 * 4);
  bf16* owb   = (bf16*)alloc((size_t)1024 * 1024 * 2);
  bf16* qkvb  = (bf16*)alloc((size_t)4096 * 3072 * 2);
  float* ct   = (float*)alloc((size_t)SEQ * 32 * 4);
  float* st   = (float*)alloc((size_t)SEQ * 32 * 4);
  bf16* Qrb   = (bf16*)alloc((size_t)NB * NHD * SEQ * 64 * 2);
  bf16* Knb   = (bf16*)alloc((size_t)NB * NHD * SEQ * 64 * 2);
  bf16* Vtb   = (bf16*)alloc((size_t)NB * NHD * 64 * SEQ * 2);
  bf16* AOb   = (bf16*)alloc((size_t)4096 * 1024 * 2);

  prep_wqkv<<<dim3(3072 * 1024 / 256), 256, 0, stream>>>(qw, kw, vw, qA, qB, vA, vB, Wqkv);
  cvt_swz<<<dim3(4096 * 1024 / 256), 256, 0, stream>>>(hs, hsb, 4096 * 1024, 1024);
  cvt_swz<<<dim3(1024 * 1024 / 256), 256, 0, stream>>>(ow, owb, 1024 * 1024, 1024);
  bias_cat<<<dim3(12), 256, 0, stream>>>(qb_, kb_, vb_, bqkv);
  rope_tab<<<dim3(SEQ * 32 / 256), 256, 0, stream>>>(ct, st);
  gemm_bt<<<dim3(3072 / 128, 4096 / 128), 256, 0, stream>>>(
      hsb, Wqkv, bqkv, qkvb, nullptr, 4096, 3072, 1024);
  rope_q<<<dim3(NB * NHD * SEQ * 32 / 256), 256, 0, stream>>>(qkvb, pos, ct, st, Qrb);
  holo_kv<<<dim3(NB * NHD * (SEQ / 4) * 32 / 256), 256, 0, stream>>>(
      qkvb, pos, ct, st, cd, Knb, Vtb);
  attn_fwd<<<dim3(16, NHD, NB), 256, 0, stream>>>(Qrb, Knb, Vtb, AOb);
  gemm_bt<<<dim3(1024 / 128, 4096 / 128), 256, 0, stream>>>(
      AOb, owb, nullptr, nullptr, (float*)d_out, 4096, 1024, 1024);
}

// Round 9
// 166.298 us; speedup vs baseline: 1.2183x; 1.0602x over previous
//
#include <hip/hip_runtime.h>
#include <hip/hip_bf16.h>
#include <math.h>

// ---------------------------------------------------------------------------
// HoloKVSimulatorLayer fused pipeline, bf16 MFMA, MI355X (gfx950)
//   B=2 S=2048 H=1024 NH=NKV=16 HD=64 R=16 KF=4 theta=1e6
// R9: attn_fwd KVBLK=128 (17 uniform steps/paired block, fixed per-step cost
// halved), scale folded into Qr. Paired schedule + swapped QK/PV kept from R8.
// ---------------------------------------------------------------------------

typedef __bf16 bf16;
typedef __attribute__((ext_vector_type(8))) __bf16 bf16x8;
typedef __attribute__((ext_vector_type(4))) float f32x4;

#define NB 2
#define SEQ 2048
#define HID 1024
#define NHD 16
#define HDD 64

__device__ __forceinline__ void gld_lds16(const void* g, void* l) {
  __builtin_amdgcn_global_load_lds(
      (const __attribute__((address_space(1))) void*)g,
      (__attribute__((address_space(3))) void*)l, 16, 0, 0);
}

__device__ __forceinline__ unsigned pack2bf(float a, float b) {
  unsigned short ua = __builtin_bit_cast(unsigned short, (bf16)a);
  unsigned short ub = __builtin_bit_cast(unsigned short, (bf16)b);
  return ((unsigned)ub << 16) | ua;
}

// ---------------- P0: fold LoRA into weights, swizzle, bf16 ----------------
__global__ __launch_bounds__(256) void prep_wqkv(
    const float* __restrict__ qw, const float* __restrict__ kw,
    const float* __restrict__ vw, const float* __restrict__ qA,
    const float* __restrict__ qB, const float* __restrict__ vA,
    const float* __restrict__ vB, bf16* __restrict__ W) {
  int idx = blockIdx.x * 256 + threadIdx.x;   // n*1024 + k, n in [0,3072)
  if (idx >= 3072 * 1024) return;
  int n = idx >> 10, k = idx & 1023;
  float v;
  if (n < 1024) {
    v = qw[n * 1024 + k];
#pragma unroll
    for (int r = 0; r < 16; ++r) v += qB[n * 16 + r] * qA[r * 1024 + k];
  } else if (n < 2048) {
    v = kw[(n - 1024) * 1024 + k];
  } else {
    int nn = n - 2048;
    v = vw[nn * 1024 + k];
#pragma unroll
    for (int r = 0; r < 16; ++r) v += vB[nn * 16 + r] * vA[r * 1024 + k];
  }
  int seg = k >> 6, cl = k & 63;
  int ch = (cl >> 3) ^ (n & 7);
  W[(size_t)n * 1024 + (seg << 6) + (ch << 3) + (cl & 7)] = (bf16)v;
}

// ---------------- P1: f32 -> bf16 with global pre-swizzle ------------------
__global__ __launch_bounds__(256) void cvt_swz(const float* __restrict__ src,
                                               bf16* __restrict__ dst,
                                               int total, int cols) {
  int idx = blockIdx.x * 256 + threadIdx.x;
  if (idx >= total) return;
  int r = idx / cols, c = idx - r * cols;
  int seg = c >> 6, cl = c & 63;
  int ch = (cl >> 3) ^ (r & 7);
  dst[(size_t)r * cols + (seg << 6) + (ch << 3) + (cl & 7)] = (bf16)src[idx];
}

__global__ void bias_cat(const float* __restrict__ qb, const float* __restrict__ kb,
                         const float* __restrict__ vb, float* __restrict__ out) {
  int i = blockIdx.x * 256 + threadIdx.x;
  if (i >= 3072) return;
  out[i] = (i < 1024) ? qb[i] : (i < 2048 ? kb[i - 1024] : vb[i - 2048]);
}

// ---------------- P3: RoPE cos/sin table [2048][32] ------------------------
__global__ void rope_tab(float* __restrict__ ct, float* __restrict__ st) {
  int idx = blockIdx.x * 256 + threadIdx.x;
  if (idx >= SEQ * 32) return;
  int s = idx >> 5, i = idx & 31;
  double inv = pow(1.0e6, -(double)i / 32.0);
  double a = (double)s * inv;
  ct[idx] = (float)cos(a);
  st[idx] = (float)sin(a);
}

// ---------------- K1/K5: bf16 MFMA GEMM, C = A @ Bw^T (+bias) --------------
__global__ __launch_bounds__(256) void gemm_bt(
    const bf16* __restrict__ A, const bf16* __restrict__ Bw,
    const float* __restrict__ bias, bf16* __restrict__ Cb,
    float* __restrict__ Cf, int M, int N, int K) {
  __shared__ __align__(16) bf16 As[128 * 64];
  __shared__ __align__(16) bf16 Bs[128 * 64];
  const int tid = threadIdx.x;
  const int lane = tid & 63, w = tid >> 6;
  const int wm = w >> 1, wn = w & 1;
  const int l15 = lane & 15, l4 = lane >> 4;
  const int m0 = blockIdx.y * 128, n0 = blockIdx.x * 128;
  const size_t rowb = (size_t)K * 2;
  const char* gA = (const char*)A + (size_t)m0 * rowb;
  const char* gB = (const char*)Bw + (size_t)n0 * rowb;
  f32x4 acc[4][4] = {};

  for (int k0 = 0; k0 < K; k0 += 64) {
    const char* gAk = gA + k0 * 2;
    const char* gBk = gB + k0 * 2;
#pragma unroll
    for (int i = 0; i < 4; ++i) {
      int idx = i * 256 + tid;
      int row = idx >> 3, ch = idx & 7;
      gld_lds16(gAk + (size_t)row * rowb + ch * 16,
                (char*)As + (i * 256 + (w << 6)) * 16);
      gld_lds16(gBk + (size_t)row * rowb + ch * 16,
                (char*)Bs + (i * 256 + (w << 6)) * 16);
    }
    __syncthreads();
#pragma unroll
    for (int c = 0; c < 2; ++c) {
      bf16x8 af[4], bfr[4];
#pragma unroll
      for (int mi = 0; mi < 4; ++mi) {
        int row = wm * 64 + mi * 16 + l15;
        int ch = (c * 4 + l4) ^ (row & 7);
        af[mi] = *(const bf16x8*)(As + row * 64 + ch * 8);
      }
#pragma unroll
      for (int ni = 0; ni < 4; ++ni) {
        int row = wn * 64 + ni * 16 + l15;
        int ch = (c * 4 + l4) ^ (row & 7);
        bfr[ni] = *(const bf16x8*)(Bs + row * 64 + ch * 8);
      }
#pragma unroll
      for (int mi = 0; mi < 4; ++mi)
#pragma unroll
        for (int ni = 0; ni < 4; ++ni)
          acc[mi][ni] = __builtin_amdgcn_mfma_f32_16x16x32_bf16(
              af[mi], bfr[ni], acc[mi][ni], 0, 0, 0);
    }
    __syncthreads();
  }
#pragma unroll
  for (int mi = 0; mi < 4; ++mi) {
    int rbase = m0 + wm * 64 + mi * 16 + l4 * 4;
#pragma unroll
    for (int ni = 0; ni < 4; ++ni) {
      int col = n0 + wn * 64 + ni * 16 + l15;
      float badd = bias ? bias[col] : 0.0f;
#pragma unroll
      for (int r = 0; r < 4; ++r) {
        float v = acc[mi][ni][r] + badd;
        if (Cf) Cf[(size_t)(rbase + r) * N + col] = v;
        else    Cb[(size_t)(rbase + r) * N + col] = (bf16)v;
      }
    }
  }
}

// ---------------- K2: RoPE on q -> Qr [B,NH,S,HD], pre-scaled --------------
__global__ __launch_bounds__(256) void rope_q(
    const bf16* __restrict__ qkv, const int* __restrict__ pos,
    const float* __restrict__ ct, const float* __restrict__ st,
    bf16* __restrict__ Qr) {
  const float SCQ = 0.0901684403f;  // (1/16) * log2(e), folded attn scale
  int idx = blockIdx.x * 256 + threadIdx.x;  // [b][s][h][i]
  if (idx >= NB * NHD * SEQ * 32) return;
  int i = idx & 31, h = (idx >> 5) & 15, s = (idx >> 9) & 2047, b = idx >> 20;
  int p = pos[b * SEQ + s];
  float co = ct[p * 32 + i], sn = st[p * 32 + i];
  size_t base = ((size_t)(b * SEQ + s)) * 3072 + h * 64 + i;
  float x = (float)qkv[base], y = (float)qkv[base + 32];
  size_t ob = ((size_t)((b * 16 + h) * SEQ + s)) * 64 + i;
  Qr[ob]      = (bf16)((x * co - y * sn) * SCQ);
  Qr[ob + 32] = (bf16)((y * co + x * sn) * SCQ);
}

// ---------------- K3: RoPE(k) + holographic bind/sum -----------------------
__global__ __launch_bounds__(256) void holo_kv(
    const bf16* __restrict__ qkv, const int* __restrict__ pos,
    const float* __restrict__ ct, const float* __restrict__ st,
    const float* __restrict__ cdma, bf16* __restrict__ Kn,
    bf16* __restrict__ Vt) {
  int idx = blockIdx.x * 256 + threadIdx.x;  // [b][h][slot][i]
  if (idx >= NB * NHD * (SEQ / 4) * 32) return;
  int i = idx & 31, slot = (idx >> 5) & 511, h = (idx >> 14) & 15, b = idx >> 18;
  float c[4];
  float SK = 0.f, SK2 = 0.f, SV = 0.f, SV2 = 0.f;
#pragma unroll
  for (int f = 0; f < 4; ++f) {
    int s = slot * 4 + f;
    float cf = cdma[f * 64 + i];
    c[f] = cf;
    size_t base = ((size_t)(b * SEQ + s)) * 3072 + h * 64 + i;
    float kx = (float)qkv[base + 1024], ky = (float)qkv[base + 1024 + 32];
    int p = pos[b * SEQ + s];
    float co = ct[p * 32 + i], sn = st[p * 32 + i];
    SK  += (kx * co - ky * sn) * cf;
    SK2 += (ky * co + kx * sn) * cf;
    SV  += (float)qkv[base + 2048] * cf;
    SV2 += (float)qkv[base + 2048 + 32] * cf;
  }
  size_t hb = (size_t)(b * 16 + h);
#pragma unroll
  for (int f = 0; f < 4; ++f) {
    int s = slot * 4 + f;
    size_t krow = (hb * SEQ + s) * 64;
    int ch0 = (i >> 3) ^ (s & 7);
    int ch1 = (4 + (i >> 3)) ^ (s & 7);
    Kn[krow + ch0 * 8 + (i & 7)] = (bf16)(SK * c[f]);
    Kn[krow + ch1 * 8 + (i & 7)] = (bf16)(SK2 * c[f]);
    int seg = s >> 6, cl = s & 63;
    int vch = (cl >> 3) ^ (i & 7);
    size_t vrow0 = (hb * 64 + i) * (size_t)SEQ + (seg << 6);
    size_t vrow1 = (hb * 64 + i + 32) * (size_t)SEQ + (seg << 6);
    Vt[vrow0 + vch * 8 + (cl & 7)] = (bf16)(SV * c[f]);
    Vt[vrow1 + vch * 8 + (cl & 7)] = (bf16)(SV2 * c[f]);
  }
}

// ---------------- K4: causal flash attention (R9, KVBLK=128) ---------------
// grid (16 pairs, h=16, b=2); block does q-tiles {pq, 31-pq}; nt=(qt>>1)+1
// KV-tiles of 128 each -> 17 steps total per block, uniform.
__global__ __launch_bounds__(256) void attn_fwd(
    const bf16* __restrict__ Qr, const bf16* __restrict__ Kn,
    const bf16* __restrict__ Vt, bf16* __restrict__ AO) {
  __shared__ __align__(16) bf16 Kt[2][128 * 64];   // kv x d, 16KB each
  __shared__ __align__(16) bf16 Vl[2][64 * 128];   // d x kv, 16KB each
  __shared__ __align__(16) bf16 Pt[4][16 * 128];   // q x kv per wave, 4KB
  const int pq = blockIdx.x, h = blockIdx.y, b = blockIdx.z;
  const int tid = threadIdx.x, lane = tid & 63, w = tid >> 6;
  const int l15 = lane & 15, l4 = lane >> 4;
  const size_t hd = ((size_t)(b * 16 + h)) * SEQ * 64;
  const char* gK0 = (const char*)(Kn + hd);
  const char* gV0 = (const char*)(Vt + hd);
  char* pw = (char*)&Pt[w][0];

#pragma unroll 1
  for (int phase = 0; phase < 2; ++phase) {
    const int qt = phase ? (31 - pq) : pq;
    const int q0 = qt * 64;
    const int qg = q0 + w * 16 + l15;  // this lane's q row
    const int nt = (qt >> 1) + 1;

    const bf16* qb = Qr + hd + (size_t)qg * 64;
    bf16x8 qf0 = *(const bf16x8*)(qb + l4 * 8);
    bf16x8 qf1 = *(const bf16x8*)(qb + 32 + l4 * 8);

    f32x4 oacc[4] = {};        // O^T: d = df*16 + l4*4 + r, q = l15
    float m = -1e30f, lsum = 0.0f;

    // prologue: stage tile 0 (K linear 16KB; V 64 rows x 256B)
#pragma unroll
    for (int i = 0; i < 4; ++i)
      gld_lds16(gK0 + (i * 256 + tid) * 16,
                (char*)Kt[0] + (i * 256 + (w << 6)) * 16);
#pragma unroll
    for (int i = 0; i < 4; ++i) {
      int idx = i * 256 + tid;
      int row = idx >> 4, ch = idx & 15;
      gld_lds16(gV0 + (size_t)row * (SEQ * 2) + ch * 16,
                (char*)Vl[0] + (i * 256 + (w << 6)) * 16);
    }

#pragma unroll 1
    for (int t = 0; t < nt; ++t) {
      const int cur = t & 1;
      if (t + 1 < nt) {
        const int tn = t + 1, sb = cur ^ 1;
#pragma unroll
        for (int i = 0; i < 4; ++i)
          gld_lds16(gK0 + (size_t)tn * 16384 + (i * 256 + tid) * 16,
                    (char*)Kt[sb] + (i * 256 + (w << 6)) * 16);
#pragma unroll
        for (int i = 0; i < 4; ++i) {
          int idx = i * 256 + tid;
          int row = idx >> 4, ch = idx & 15;
          gld_lds16(gV0 + (size_t)row * (SEQ * 2) + tn * 256 + ch * 16,
                    (char*)Vl[sb] + (i * 256 + (w << 6)) * 16);
        }
        asm volatile("s_waitcnt vmcnt(8)\ns_barrier" ::: "memory");
      } else {
        asm volatile("s_waitcnt vmcnt(0)\ns_barrier" ::: "memory");
      }

      const bf16* Ktc = Kt[cur];
      const bf16* Vlc = Vl[cur];
      const int kv0 = t * 128;
      const bool lastt = (t == nt - 1);

      // QK^T swapped (pre-scaled Q): col=l15=q, kv = nf*16 + l4*4 + r
      f32x4 sacc[8] = {};
#pragma unroll
      for (int c = 0; c < 2; ++c) {
        bf16x8 qf = c ? qf1 : qf0;
#pragma unroll
        for (int nf = 0; nf < 8; ++nf) {
          int row = nf * 16 + l15;
          int ch = (c * 4 + l4) ^ (row & 7);
          bf16x8 kf = *(const bf16x8*)(Ktc + row * 64 + ch * 8);
          sacc[nf] = __builtin_amdgcn_mfma_f32_16x16x32_bf16(kf, qf, sacc[nf], 0, 0, 0);
        }
      }

      // causal mask (last tile only) + in-lane max
      float pmax = -1e30f;
      if (lastt) {
#pragma unroll
        for (int nf = 0; nf < 8; ++nf)
#pragma unroll
          for (int r = 0; r < 4; ++r) {
            int kvg = kv0 + nf * 16 + l4 * 4 + r;
            float v = (kvg > qg) ? -1e30f : sacc[nf][r];
            sacc[nf][r] = v;
            pmax = fmaxf(pmax, v);
          }
      } else {
#pragma unroll
        for (int nf = 0; nf < 8; ++nf)
#pragma unroll
          for (int r = 0; r < 4; ++r) pmax = fmaxf(pmax, sacc[nf][r]);
      }
      pmax = fmaxf(pmax, __shfl_xor(pmax, 16));
      pmax = fmaxf(pmax, __shfl_xor(pmax, 32));

      // online stats; exact skip when no row's max grew
      if (!__all(pmax <= m)) {
        float mn = fmaxf(m, pmax);
        float al = exp2f(m - mn);
        m = mn;
        lsum *= al;
#pragma unroll
        for (int df = 0; df < 4; ++df) oacc[df] *= al;
      }
      float rs = 0.0f;
#pragma unroll
      for (int nf = 0; nf < 8; ++nf)
#pragma unroll
        for (int r = 0; r < 4; ++r) {
          float e = exp2f(sacc[nf][r] - m);
          sacc[nf][r] = e;
          rs += e;
        }
      rs += __shfl_xor(rs, 16);
      rs += __shfl_xor(rs, 32);
      lsum += rs;

      // P (q=l15 row, 256B/row) -> swizzled wave-private LDS, packed b32
#pragma unroll
      for (int nf = 0; nf < 8; ++nf)
#pragma unroll
        for (int rp = 0; rp < 2; ++rp) {
          unsigned u = pack2bf(sacc[nf][rp * 2], sacc[nf][rp * 2 + 1]);
          int boff = l15 * 256 + nf * 32 + l4 * 8 + rp * 4;
          boff ^= (l15 & 7) << 4;
          *(unsigned*)(pw + boff) = u;
        }

      // PV swapped: oacc = V^T·P^T over 4 k-slabs of 32
#pragma unroll
      for (int c2 = 0; c2 < 4; ++c2) {
        int pb = (l15 * 256 + c2 * 64 + l4 * 16) ^ ((l15 & 7) << 4);
        bf16x8 pf = *(const bf16x8*)(pw + pb);
        int vbyte = (c2 * 64 + l4 * 16) ^ ((l15 & 7) << 4);
#pragma unroll
        for (int df = 0; df < 4; ++df) {
          int vrow = df * 16 + l15;
          bf16x8 vf = *(const bf16x8*)((const char*)Vlc + vrow * 256 + vbyte);
          oacc[df] = __builtin_amdgcn_mfma_f32_16x16x32_bf16(vf, pf, oacc[df], 0, 0, 0);
        }
      }
      asm volatile("s_barrier" ::: "memory");
    }

    // epilogue: O^T[d][q=l15] -> AO[q][h*64+d] (preswizzled for K5, key q&7)
    const float li = 1.0f / lsum;
    const size_t arow = ((size_t)(b * SEQ + qg)) * HID + h * 64;
    const int qk7 = qg & 7;
#pragma unroll
    for (int df = 0; df < 4; ++df)
#pragma unroll
      for (int r = 0; r < 4; ++r) {
        int d = df * 16 + l4 * 4 + r;
        int ch = (d >> 3) ^ qk7;
        AO[arow + ch * 8 + (d & 7)] = (bf16)(oacc[df][r] * li);
      }
  }
}

// ---------------------------------------------------------------------------
extern "C" void kernel_launch(void* const* d_in, const int* in_sizes, int n_in,
                              void* d_out, int out_size, void* d_ws, size_t ws_size,
                              hipStream_t stream) {
  const float* hs  = (const float*)d_in[0];
  const int* pos   = (const int*)d_in[1];
  const float* qw  = (const float*)d_in[2];
  const float* qb_ = (const float*)d_in[3];
  const float* kw  = (const float*)d_in[4];
  const float* kb_ = (const float*)d_in[5];
  const float* vw  = (const float*)d_in[6];
  const float* vb_ = (const float*)d_in[7];
  const float* ow  = (const float*)d_in[8];
  const float* qA  = (const float*)d_in[9];
  const float* qB  = (const float*)d_in[10];
  const float* vA  = (const float*)d_in[11];
  const float* vB  = (const float*)d_in[12];
  const float* cd  = (const float*)d_in[13];

  char* p = (char*)d_ws;
  auto alloc = [&](size_t bytes) {
    char* r = p; p += (bytes + 255) & ~(size_t)255; return r;
  };
  bf16* hsb   = (bf16*)alloc((size_t)4096 * 1024 * 2);
  bf16* Wqkv  = (bf16*)alloc((size_t)3072 * 1024 * 2);
  float* bqkv = (float*)alloc(3072 * 4);
  bf16* owb   = (bf16*)alloc((size_t)1024 * 1024 * 2);
  bf16* qkvb  = (bf16*)alloc((size_t)4096 * 3072 * 2);
  float* ct   = (float*)alloc((size_t)SEQ * 32 * 4);
  float* st   = (float*)alloc((size_t)SEQ * 32 * 4);
  bf16* Qrb   = (bf16*)alloc((size_t)NB * NHD * SEQ * 64 * 2);
  bf16* Knb   = (bf16*)alloc((size_t)NB * NHD * SEQ * 64 * 2);
  bf16* Vtb   = (bf16*)alloc((size_t)NB * NHD * 64 * SEQ * 2);
  bf16* AOb   = (bf16*)alloc((size_t)4096 * 1024 * 2);

  prep_wqkv<<<dim3(3072 * 1024 / 256), 256, 0, stream>>>(qw, kw, vw, qA, qB, vA, vB, Wqkv);
  cvt_swz<<<dim3(4096 * 1024 / 256), 256, 0, stream>>>(hs, hsb, 4096 * 1024, 1024);
  cvt_swz<<<dim3(1024 * 1024 / 256), 256, 0, stream>>>(ow, owb, 1024 * 1024, 1024);
  bias_cat<<<dim3(12), 256, 0, stream>>>(qb_, kb_, vb_, bqkv);
  rope_tab<<<dim3(SEQ * 32 / 256), 256, 0, stream>>>(ct, st);
  gemm_bt<<<dim3(3072 / 128, 4096 / 128), 256, 0, stream>>>(
      hsb, Wqkv, bqkv, qkvb, nullptr, 4096, 3072, 1024);
  rope_q<<<dim3(NB * NHD * SEQ * 32 / 256), 256, 0, stream>>>(qkvb, pos, ct, st, Qrb);
  holo_kv<<<dim3(NB * NHD * (SEQ / 4) * 32 / 256), 256, 0, stream>>>(
      qkvb, pos, ct, st, cd, Knb, Vtb);
  attn_fwd<<<dim3(16, NHD, NB), 256, 0, stream>>>(Qrb, Knb, Vtb, AOb);
  gemm_bt<<<dim3(1024 / 128, 4096 / 128), 256, 0, stream>>>(
      AOb, owb, nullptr, nullptr, (float*)d_out, 4096, 1024, 1024);
}

// Round 10
// 158.207 us; speedup vs baseline: 1.2806x; 1.0511x over previous
//
#include <hip/hip_runtime.h>
#include <hip/hip_bf16.h>
#include <math.h>

// ---------------------------------------------------------------------------
// HoloKVSimulatorLayer fused pipeline, bf16 MFMA, MI355X (gfx950)
//   B=2 S=2048 H=1024 NH=NKV=16 HD=64 R=16 KF=4 theta=1e6
// R10: prep kernels merged (10->6 launches); rope_q/holo_kv vectorized bf16x8;
// attn: b64 P-stores (halve bank conflicts), 4-acc softmax reductions.
// ---------------------------------------------------------------------------

typedef __bf16 bf16;
typedef __attribute__((ext_vector_type(8))) __bf16 bf16x8;
typedef __attribute__((ext_vector_type(4))) float f32x4;
typedef __attribute__((ext_vector_type(2))) unsigned u32x2;

#define NB 2
#define SEQ 2048
#define HID 1024
#define NHD 16
#define HDD 64

__device__ __forceinline__ void gld_lds16(const void* g, void* l) {
  __builtin_amdgcn_global_load_lds(
      (const __attribute__((address_space(1))) void*)g,
      (__attribute__((address_space(3))) void*)l, 16, 0, 0);
}

__device__ __forceinline__ unsigned pack2bf(float a, float b) {
  unsigned short ua = __builtin_bit_cast(unsigned short, (bf16)a);
  unsigned short ub = __builtin_bit_cast(unsigned short, (bf16)b);
  return ((unsigned)ub << 16) | ua;
}

// ---------------- P*: all preprocessing in one region-dispatched kernel ----
// regions: [0,12288) Wqkv prep | [12288,28672) hs cvt | [28672,32768) ow cvt
//          [32768,32780) bias  | [32780,33036) rope table
#define RB_W    12288
#define RB_HS   (RB_W + 16384)
#define RB_OW   (RB_HS + 4096)
#define RB_BIAS (RB_OW + 12)
#define RB_TAB  (RB_BIAS + 256)

__global__ __launch_bounds__(256) void prep_all(
    const float* __restrict__ hs, const float* __restrict__ ow,
    const float* __restrict__ qw, const float* __restrict__ qb,
    const float* __restrict__ kw, const float* __restrict__ kb,
    const float* __restrict__ vw, const float* __restrict__ vb,
    const float* __restrict__ qA, const float* __restrict__ qB,
    const float* __restrict__ vA, const float* __restrict__ vB,
    bf16* __restrict__ hsb, bf16* __restrict__ owb, bf16* __restrict__ Wqkv,
    float* __restrict__ bqkv, float* __restrict__ ct, float* __restrict__ st) {
  const int bid = blockIdx.x, tid = threadIdx.x;
  if (bid < RB_W) {
    int idx = bid * 256 + tid;           // n*1024 + k, n in [0,3072)
    int n = idx >> 10, k = idx & 1023;
    float v;
    if (n < 1024) {
      v = qw[n * 1024 + k];
#pragma unroll
      for (int r = 0; r < 16; ++r) v += qB[n * 16 + r] * qA[r * 1024 + k];
    } else if (n < 2048) {
      v = kw[(n - 1024) * 1024 + k];
    } else {
      int nn = n - 2048;
      v = vw[nn * 1024 + k];
#pragma unroll
      for (int r = 0; r < 16; ++r) v += vB[nn * 16 + r] * vA[r * 1024 + k];
    }
    int seg = k >> 6, cl = k & 63;
    int ch = (cl >> 3) ^ (n & 7);
    Wqkv[(size_t)n * 1024 + (seg << 6) + (ch << 3) + (cl & 7)] = (bf16)v;
  } else if (bid < RB_HS) {
    int idx = (bid - RB_W) * 256 + tid;  // r*1024 + c
    int r = idx >> 10, c = idx & 1023;
    int seg = c >> 6, cl = c & 63;
    int ch = (cl >> 3) ^ (r & 7);
    hsb[(size_t)r * 1024 + (seg << 6) + (ch << 3) + (cl & 7)] = (bf16)hs[idx];
  } else if (bid < RB_OW) {
    int idx = (bid - RB_HS) * 256 + tid;
    int r = idx >> 10, c = idx & 1023;
    int seg = c >> 6, cl = c & 63;
    int ch = (cl >> 3) ^ (r & 7);
    owb[(size_t)r * 1024 + (seg << 6) + (ch << 3) + (cl & 7)] = (bf16)ow[idx];
  } else if (bid < RB_BIAS) {
    int i = (bid - RB_OW) * 256 + tid;
    if (i < 3072)
      bqkv[i] = (i < 1024) ? qb[i] : (i < 2048 ? kb[i - 1024] : vb[i - 2048]);
  } else {
    int idx = (bid - RB_BIAS) * 256 + tid;  // s*32 + i
    int s = idx >> 5, i = idx & 31;
    double inv = pow(1.0e6, -(double)i / 32.0);
    double a = (double)s * inv;
    ct[idx] = (float)cos(a);
    st[idx] = (float)sin(a);
  }
}

// ---------------- K1/K5: bf16 MFMA GEMM, C = A @ Bw^T (+bias) --------------
__global__ __launch_bounds__(256) void gemm_bt(
    const bf16* __restrict__ A, const bf16* __restrict__ Bw,
    const float* __restrict__ bias, bf16* __restrict__ Cb,
    float* __restrict__ Cf, int M, int N, int K) {
  __shared__ __align__(16) bf16 As[128 * 64];
  __shared__ __align__(16) bf16 Bs[128 * 64];
  const int tid = threadIdx.x;
  const int lane = tid & 63, w = tid >> 6;
  const int wm = w >> 1, wn = w & 1;
  const int l15 = lane & 15, l4 = lane >> 4;
  const int m0 = blockIdx.y * 128, n0 = blockIdx.x * 128;
  const size_t rowb = (size_t)K * 2;
  const char* gA = (const char*)A + (size_t)m0 * rowb;
  const char* gB = (const char*)Bw + (size_t)n0 * rowb;
  f32x4 acc[4][4] = {};

  for (int k0 = 0; k0 < K; k0 += 64) {
    const char* gAk = gA + k0 * 2;
    const char* gBk = gB + k0 * 2;
#pragma unroll
    for (int i = 0; i < 4; ++i) {
      int idx = i * 256 + tid;
      int row = idx >> 3, ch = idx & 7;
      gld_lds16(gAk + (size_t)row * rowb + ch * 16,
                (char*)As + (i * 256 + (w << 6)) * 16);
      gld_lds16(gBk + (size_t)row * rowb + ch * 16,
                (char*)Bs + (i * 256 + (w << 6)) * 16);
    }
    __syncthreads();
#pragma unroll
    for (int c = 0; c < 2; ++c) {
      bf16x8 af[4], bfr[4];
#pragma unroll
      for (int mi = 0; mi < 4; ++mi) {
        int row = wm * 64 + mi * 16 + l15;
        int ch = (c * 4 + l4) ^ (row & 7);
        af[mi] = *(const bf16x8*)(As + row * 64 + ch * 8);
      }
#pragma unroll
      for (int ni = 0; ni < 4; ++ni) {
        int row = wn * 64 + ni * 16 + l15;
        int ch = (c * 4 + l4) ^ (row & 7);
        bfr[ni] = *(const bf16x8*)(Bs + row * 64 + ch * 8);
      }
#pragma unroll
      for (int mi = 0; mi < 4; ++mi)
#pragma unroll
        for (int ni = 0; ni < 4; ++ni)
          acc[mi][ni] = __builtin_amdgcn_mfma_f32_16x16x32_bf16(
              af[mi], bfr[ni], acc[mi][ni], 0, 0, 0);
    }
    __syncthreads();
  }
#pragma unroll
  for (int mi = 0; mi < 4; ++mi) {
    int rbase = m0 + wm * 64 + mi * 16 + l4 * 4;
#pragma unroll
    for (int ni = 0; ni < 4; ++ni) {
      int col = n0 + wn * 64 + ni * 16 + l15;
      float badd = bias ? bias[col] : 0.0f;
#pragma unroll
      for (int r = 0; r < 4; ++r) {
        float v = acc[mi][ni][r] + badd;
        if (Cf) Cf[(size_t)(rbase + r) * N + col] = v;
        else    Cb[(size_t)(rbase + r) * N + col] = (bf16)v;
      }
    }
  }
}

// ---------------- K2: RoPE on q (vectorized bf16x8), pre-scaled ------------
__global__ __launch_bounds__(256) void rope_q(
    const bf16* __restrict__ qkv, const int* __restrict__ pos,
    const float* __restrict__ ct, const float* __restrict__ st,
    bf16* __restrict__ Qr) {
  const float SCQ = 0.0901684403f;  // (1/16) * log2(e), folded attn scale
  int idx = blockIdx.x * 256 + threadIdx.x;  // [b][h][s][ih]
  if (idx >= NB * NHD * SEQ * 4) return;
  int ih = idx & 3, s = (idx >> 2) & 2047, h = (idx >> 13) & 15, b = idx >> 17;
  int p = pos[b * SEQ + s];
  size_t base = ((size_t)(b * SEQ + s)) * 3072 + h * 64 + ih * 8;
  bf16x8 xv = *(const bf16x8*)(qkv + base);
  bf16x8 yv = *(const bf16x8*)(qkv + base + 32);
  const float* ctp = ct + p * 32 + ih * 8;
  const float* stp = st + p * 32 + ih * 8;
  bf16x8 o0, o1;
#pragma unroll
  for (int e = 0; e < 8; ++e) {
    float x = (float)xv[e], y = (float)yv[e];
    float co = ctp[e], sn = stp[e];
    o0[e] = (bf16)((x * co - y * sn) * SCQ);
    o1[e] = (bf16)((y * co + x * sn) * SCQ);
  }
  size_t ob = ((size_t)((b * 16 + h) * SEQ + s)) * 64 + ih * 8;
  *(bf16x8*)(Qr + ob) = o0;
  *(bf16x8*)(Qr + ob + 32) = o1;
}

// ---------------- K3: RoPE(k) + holographic bind/sum (vectorized) ----------
__global__ __launch_bounds__(256) void holo_kv(
    const bf16* __restrict__ qkv, const int* __restrict__ pos,
    const float* __restrict__ ct, const float* __restrict__ st,
    const float* __restrict__ cdma, bf16* __restrict__ Kn,
    bf16* __restrict__ Vt) {
  int idx = blockIdx.x * 256 + threadIdx.x;  // [b][h][slot][ih]
  if (idx >= NB * NHD * (SEQ / 4) * 4) return;
  int ih = idx & 3, slot = (idx >> 2) & 511, h = (idx >> 11) & 15, b = idx >> 15;
  float SK[8] = {}, SK2[8] = {}, SV[8] = {}, SV2[8] = {};
#pragma unroll
  for (int f = 0; f < 4; ++f) {
    int s = slot * 4 + f;
    size_t base = ((size_t)(b * SEQ + s)) * 3072 + h * 64 + ih * 8;
    bf16x8 klo = *(const bf16x8*)(qkv + base + 1024);
    bf16x8 khi = *(const bf16x8*)(qkv + base + 1024 + 32);
    bf16x8 vlo = *(const bf16x8*)(qkv + base + 2048);
    bf16x8 vhi = *(const bf16x8*)(qkv + base + 2048 + 32);
    int p = pos[b * SEQ + s];
    const float* ctp = ct + p * 32 + ih * 8;
    const float* stp = st + p * 32 + ih * 8;
    const float* cdp = cdma + f * 64 + ih * 8;
#pragma unroll
    for (int e = 0; e < 8; ++e) {
      float cf = cdp[e];
      float kx = (float)klo[e], ky = (float)khi[e];
      float co = ctp[e], sn = stp[e];
      SK[e]  += (kx * co - ky * sn) * cf;
      SK2[e] += (ky * co + kx * sn) * cf;
      SV[e]  += (float)vlo[e] * cf;
      SV2[e] += (float)vhi[e] * cf;
    }
  }
  size_t hb = (size_t)(b * 16 + h);
#pragma unroll
  for (int f = 0; f < 4; ++f) {
    int s = slot * 4 + f;
    const float* cdp = cdma + f * 64 + ih * 8;
    bf16x8 k0, k1;
#pragma unroll
    for (int e = 0; e < 8; ++e) {
      k0[e] = (bf16)(SK[e] * cdp[e]);
      k1[e] = (bf16)(SK2[e] * cdp[e]);
    }
    size_t krow = (hb * SEQ + s) * 64;
    int ch0 = ih ^ (s & 7);
    int ch1 = (4 + ih) ^ (s & 7);
    *(bf16x8*)(Kn + krow + ch0 * 8) = k0;
    *(bf16x8*)(Kn + krow + ch1 * 8) = k1;
    int seg = s >> 6, cl = s & 63;
    size_t vcol = (size_t)(seg << 6) + (cl & 7);
#pragma unroll
    for (int e = 0; e < 8; ++e) {
      int i = ih * 8 + e;
      int vch = (cl >> 3) ^ (i & 7);
      Vt[(hb * 64 + i) * (size_t)SEQ + vcol + vch * 8] = (bf16)(SV[e] * cdp[e]);
      Vt[(hb * 64 + i + 32) * (size_t)SEQ + vcol + vch * 8] = (bf16)(SV2[e] * cdp[e]);
    }
  }
}

// ---------------- K4: causal flash attention (R10) -------------------------
// grid (16 pairs, h=16, b=2); q-tiles {pq, 31-pq}; KVBLK=128, 17 steps.
__global__ __launch_bounds__(256) void attn_fwd(
    const bf16* __restrict__ Qr, const bf16* __restrict__ Kn,
    const bf16* __restrict__ Vt, bf16* __restrict__ AO) {
  __shared__ __align__(16) bf16 Kt[2][128 * 64];   // kv x d
  __shared__ __align__(16) bf16 Vl[2][64 * 128];   // d x kv
  __shared__ __align__(16) bf16 Pt[4][16 * 128];   // q x kv per wave
  const int pq = blockIdx.x, h = blockIdx.y, b = blockIdx.z;
  const int tid = threadIdx.x, lane = tid & 63, w = tid >> 6;
  const int l15 = lane & 15, l4 = lane >> 4;
  const size_t hd = ((size_t)(b * 16 + h)) * SEQ * 64;
  const char* gK0 = (const char*)(Kn + hd);
  const char* gV0 = (const char*)(Vt + hd);
  char* pw = (char*)&Pt[w][0];

#pragma unroll 1
  for (int phase = 0; phase < 2; ++phase) {
    const int qt = phase ? (31 - pq) : pq;
    const int q0 = qt * 64;
    const int qg = q0 + w * 16 + l15;
    const int nt = (qt >> 1) + 1;

    const bf16* qb = Qr + hd + (size_t)qg * 64;
    bf16x8 qf0 = *(const bf16x8*)(qb + l4 * 8);
    bf16x8 qf1 = *(const bf16x8*)(qb + 32 + l4 * 8);

    f32x4 oacc[4] = {};        // O^T: d = df*16 + l4*4 + r, q = l15
    float m = -1e30f, lsum = 0.0f;

    // prologue: stage tile 0
#pragma unroll
    for (int i = 0; i < 4; ++i)
      gld_lds16(gK0 + (i * 256 + tid) * 16,
                (char*)Kt[0] + (i * 256 + (w << 6)) * 16);
#pragma unroll
    for (int i = 0; i < 4; ++i) {
      int idx = i * 256 + tid;
      int row = idx >> 4, ch = idx & 15;
      gld_lds16(gV0 + (size_t)row * (SEQ * 2) + ch * 16,
                (char*)Vl[0] + (i * 256 + (w << 6)) * 16);
    }

#pragma unroll 1
    for (int t = 0; t < nt; ++t) {
      const int cur = t & 1;
      if (t + 1 < nt) {
        const int tn = t + 1, sb = cur ^ 1;
#pragma unroll
        for (int i = 0; i < 4; ++i)
          gld_lds16(gK0 + (size_t)tn * 16384 + (i * 256 + tid) * 16,
                    (char*)Kt[sb] + (i * 256 + (w << 6)) * 16);
#pragma unroll
        for (int i = 0; i < 4; ++i) {
          int idx = i * 256 + tid;
          int row = idx >> 4, ch = idx & 15;
          gld_lds16(gV0 + (size_t)row * (SEQ * 2) + tn * 256 + ch * 16,
                    (char*)Vl[sb] + (i * 256 + (w << 6)) * 16);
        }
        asm volatile("s_waitcnt vmcnt(8)\ns_barrier" ::: "memory");
      } else {
        asm volatile("s_waitcnt vmcnt(0)\ns_barrier" ::: "memory");
      }

      const bf16* Ktc = Kt[cur];
      const bf16* Vlc = Vl[cur];
      const int kv0 = t * 128;
      const bool lastt = (t == nt - 1);

      // QK^T swapped (pre-scaled Q): col=l15=q, kv = nf*16 + l4*4 + r
      f32x4 sacc[8] = {};
#pragma unroll
      for (int c = 0; c < 2; ++c) {
        bf16x8 qf = c ? qf1 : qf0;
#pragma unroll
        for (int nf = 0; nf < 8; ++nf) {
          int row = nf * 16 + l15;
          int ch = (c * 4 + l4) ^ (row & 7);
          bf16x8 kf = *(const bf16x8*)(Ktc + row * 64 + ch * 8);
          sacc[nf] = __builtin_amdgcn_mfma_f32_16x16x32_bf16(kf, qf, sacc[nf], 0, 0, 0);
        }
      }

      // causal mask (last tile only) + 4-acc max tree
      float px[4] = {-1e30f, -1e30f, -1e30f, -1e30f};
      if (lastt) {
#pragma unroll
        for (int nf = 0; nf < 8; ++nf)
#pragma unroll
          for (int r = 0; r < 4; ++r) {
            int kvg = kv0 + nf * 16 + l4 * 4 + r;
            float v = (kvg > qg) ? -1e30f : sacc[nf][r];
            sacc[nf][r] = v;
            px[nf & 3] = fmaxf(px[nf & 3], v);
          }
      } else {
#pragma unroll
        for (int nf = 0; nf < 8; ++nf)
#pragma unroll
          for (int r = 0; r < 4; ++r) px[nf & 3] = fmaxf(px[nf & 3], sacc[nf][r]);
      }
      float pmax = fmaxf(fmaxf(px[0], px[1]), fmaxf(px[2], px[3]));
      pmax = fmaxf(pmax, __shfl_xor(pmax, 16));
      pmax = fmaxf(pmax, __shfl_xor(pmax, 32));

      // online stats; exact skip when no row's max grew
      if (!__all(pmax <= m)) {
        float mn = fmaxf(m, pmax);
        float al = exp2f(m - mn);
        m = mn;
        lsum *= al;
#pragma unroll
        for (int df = 0; df < 4; ++df) oacc[df] *= al;
      }
      float rs4[4] = {0.f, 0.f, 0.f, 0.f};
#pragma unroll
      for (int nf = 0; nf < 8; ++nf)
#pragma unroll
        for (int r = 0; r < 4; ++r) {
          float e = exp2f(sacc[nf][r] - m);
          sacc[nf][r] = e;
          rs4[nf & 3] += e;
        }
      float rs = (rs4[0] + rs4[1]) + (rs4[2] + rs4[3]);
      rs += __shfl_xor(rs, 16);
      rs += __shfl_xor(rs, 32);
      lsum += rs;

      // P (q=l15 row, 256B/row) -> swizzled wave-private LDS, packed b64
#pragma unroll
      for (int nf = 0; nf < 8; ++nf) {
        u32x2 u;
        u.x = pack2bf(sacc[nf][0], sacc[nf][1]);
        u.y = pack2bf(sacc[nf][2], sacc[nf][3]);
        int boff = (l15 * 256 + nf * 32 + l4 * 8) ^ ((l15 & 7) << 4);
        *(u32x2*)(pw + boff) = u;
      }

      // PV swapped: oacc = V^T·P^T over 4 k-slabs of 32
#pragma unroll
      for (int c2 = 0; c2 < 4; ++c2) {
        int pb = (l15 * 256 + c2 * 64 + l4 * 16) ^ ((l15 & 7) << 4);
        bf16x8 pf = *(const bf16x8*)(pw + pb);
        int vbyte = (c2 * 64 + l4 * 16) ^ ((l15 & 7) << 4);
#pragma unroll
        for (int df = 0; df < 4; ++df) {
          int vrow = df * 16 + l15;
          bf16x8 vf = *(const bf16x8*)((const char*)Vlc + vrow * 256 + vbyte);
          oacc[df] = __builtin_amdgcn_mfma_f32_16x16x32_bf16(vf, pf, oacc[df], 0, 0, 0);
        }
      }
      asm volatile("s_barrier" ::: "memory");
    }

    // epilogue: O^T[d][q=l15] -> AO[q][h*64+d] (preswizzled for K5, key q&7)
    const float li = 1.0f / lsum;
    const size_t arow = ((size_t)(b * SEQ + qg)) * HID + h * 64;
    const int qk7 = qg & 7;
#pragma unroll
    for (int df = 0; df < 4; ++df)
#pragma unroll
      for (int r = 0; r < 4; ++r) {
        int d = df * 16 + l4 * 4 + r;
        int ch = (d >> 3) ^ qk7;
        AO[arow + ch * 8 + (d & 7)] = (bf16)(oacc[df][r] * li);
      }
  }
}

// ---------------------------------------------------------------------------
extern "C" void kernel_launch(void* const* d_in, const int* in_sizes, int n_in,
                              void* d_out, int out_size, void* d_ws, size_t ws_size,
                              hipStream_t stream) {
  const float* hs  = (const float*)d_in[0];
  const int* pos   = (const int*)d_in[1];
  const float* qw  = (const float*)d_in[2];
  const float* qb_ = (const float*)d_in[3];
  const float* kw  = (const float*)d_in[4];
  const float* kb_ = (const float*)d_in[5];
  const float* vw  = (const float*)d_in[6];
  const float* vb_ = (const float*)d_in[7];
  const float* ow  = (const float*)d_in[8];
  const float* qA  = (const float*)d_in[9];
  const float* qB  = (const float*)d_in[10];
  const float* vA  = (const float*)d_in[11];
  const float* vB  = (const float*)d_in[12];
  const float* cd  = (const float*)d_in[13];

  char* p = (char*)d_ws;
  auto alloc = [&](size_t bytes) {
    char* r = p; p += (bytes + 255) & ~(size_t)255; return r;
  };
  bf16* hsb   = (bf16*)alloc((size_t)4096 * 1024 * 2);
  bf16* Wqkv  = (bf16*)alloc((size_t)3072 * 1024 * 2);
  float* bqkv = (float*)alloc(3072 * 4);
  bf16* owb   = (bf16*)alloc((size_t)1024 * 1024 * 2);
  bf16* qkvb  = (bf16*)alloc((size_t)4096 * 3072 * 2);
  float* ct   = (float*)alloc((size_t)SEQ * 32 * 4);
  float* st   = (float*)alloc((size_t)SEQ * 32 * 4);
  bf16* Qrb   = (bf16*)alloc((size_t)NB * NHD * SEQ * 64 * 2);
  bf16* Knb   = (bf16*)alloc((size_t)NB * NHD * SEQ * 64 * 2);
  bf16* Vtb   = (bf16*)alloc((size_t)NB * NHD * 64 * SEQ * 2);
  bf16* AOb   = (bf16*)alloc((size_t)4096 * 1024 * 2);

  prep_all<<<dim3(RB_TAB), 256, 0, stream>>>(
      hs, ow, qw, qb_, kw, kb_, vw, vb_, qA, qB, vA, vB,
      hsb, owb, Wqkv, bqkv, ct, st);
  gemm_bt<<<dim3(3072 / 128, 4096 / 128), 256, 0, stream>>>(
      hsb, Wqkv, bqkv, qkvb, nullptr, 4096, 3072, 1024);
  rope_q<<<dim3(NB * NHD * SEQ * 4 / 256), 256, 0, stream>>>(qkvb, pos, ct, st, Qrb);
  holo_kv<<<dim3(NB * NHD * (SEQ / 4) * 4 / 256), 256, 0, stream>>>(
      qkvb, pos, ct, st, cd, Knb, Vtb);
  attn_fwd<<<dim3(16, NHD, NB), 256, 0, stream>>>(Qrb, Knb, Vtb, AOb);
  gemm_bt<<<dim3(1024 / 128, 4096 / 128), 256, 0, stream>>>(
      AOb, owb, nullptr, nullptr, (float*)d_out, 4096, 1024, 1024);
}